// Round 5
// baseline (348.351 us; speedup 1.0000x reference)
//
#include <hip/hip_runtime.h>

// GatedMoE on MI355X (gfx950), fp16 MFMA path, round 5.
// vs r4: one fused prep kernel (cvt W1 + cvt W2 + router with transposed-Wg
// LDS, 16 tok/block, fused out-row zeroing); memset dispatch deleted;
// 4 dispatches total. GEMMs unchanged (gemm1 at ~92% of its structural plateau).

typedef _Float16 half8 __attribute__((ext_vector_type(8)));
typedef _Float16 half4t __attribute__((ext_vector_type(4)));
typedef float f4 __attribute__((ext_vector_type(4)));

#define N_TOK 4096
#define DDIM  768
#define HDIM  2048
#define NEXP  8
#define CAP   614   // int(1.2 * 4096 / 8)
#define CAPP  640

// ---- workspace layout (bytes) ----
#define XH_OFF    0L           // (4097*768) fp16
#define W1T_OFF   6292992L     // [8][4096][768] fp16
#define W2T_OFF   56624640L    // [8][768][2048] fp16
#define ACT_OFF   81790464L    // [16][640][2048] fp16
#define EIDX_OFF  123733504L   // [4096][2] int
#define WTS_OFF   123766272L   // [4096][2] float
#define TOKL_OFF  123799040L   // [16][640] int
#define CNT_OFF   123840000L   // [16] int

#define CVT1_BLOCKS 6144       // W1: 12 x 64 x 8
#define CVT2_BLOCKS 3072       // W2: 32 x 12 x 8
#define ROUT_BLOCKS 257        // 16 tokens each (covers 4096 + pad row)

__device__ __forceinline__ void gld16(const void* g, void* l) {
  __builtin_amdgcn_global_load_lds(
      (const __attribute__((address_space(1))) unsigned int*)g,
      (__attribute__((address_space(3))) unsigned int*)l, 16, 0, 0);
}

// transpose+convert one 64x64 tile: src fp32 [e][R][C] -> dst fp16 [e][C][R]
__device__ __forceinline__ void cvt_tile(const float* __restrict__ src,
                                         _Float16* __restrict__ dst,
                                         int R, int C, int r0, int c0, int e,
                                         float* tile /* 64*69 floats */) {
  long sb = (long)e * R * C;
  int t = threadIdx.x;
  int rrow = t >> 4, c4 = (t & 15) * 4;
#pragma unroll
  for (int i = 0; i < 4; i++) {
    int row = i * 16 + rrow;
    f4 v = *(const f4*)(src + sb + (long)(r0 + row) * C + c0 + c4);
    *(f4*)(&tile[row * 69 + c4]) = v;
  }
  __syncthreads();
#pragma unroll
  for (int s = 0; s < 2; s++) {
    int idx = t + s * 256;
    int c = idx >> 3, ch = idx & 7;
    half8 h;
#pragma unroll
    for (int j = 0; j < 8; j++) h[j] = (_Float16)tile[(ch * 8 + j) * 69 + c];
    *(half8*)(dst + sb + (long)(c0 + c) * R + r0 + ch * 8) = h;
  }
}

// -------------------- fused prep: cvt W1 | cvt W2 | router --------------------
__global__ __launch_bounds__(256) void prep_kernel(const float* __restrict__ x,
                                                   const float* __restrict__ Wg,
                                                   const float* __restrict__ W1,
                                                   const float* __restrict__ W2,
                                                   _Float16* __restrict__ xh,
                                                   _Float16* __restrict__ w1t,
                                                   _Float16* __restrict__ w2t,
                                                   int* __restrict__ eidx,
                                                   float* __restrict__ wts,
                                                   float* __restrict__ out) {
  __shared__ float smem[DDIM * NEXP];   // 24 KB (cvt uses first 4416 floats)
  int bid = blockIdx.x;
  int t = threadIdx.x;

  if (bid < CVT1_BLOCKS) {
    int bx = bid % 12, by = (bid / 12) & 63, e = bid / 768;
    cvt_tile(W1, w1t, DDIM, 2 * HDIM, bx * 64, by * 64, e, smem);
    return;
  }
  if (bid < CVT1_BLOCKS + CVT2_BLOCKS) {
    int b2 = bid - CVT1_BLOCKS;
    int bx = b2 & 31, by = (b2 >> 5) % 12, e = b2 / 384;
    cvt_tile(W2, w2t, HDIM, DDIM, bx * 64, by * 64, e, smem);
    return;
  }

  // ---- router ----
  int rb = bid - (CVT1_BLOCKS + CVT2_BLOCKS);
  // stage Wg transposed: smem[e*768 + d]  (conflict-free logit reads)
  for (int i = t; i < DDIM * NEXP; i += 256)
    smem[(i & 7) * DDIM + (i >> 3)] = Wg[i];
  __syncthreads();

  int w = t >> 6, lane = t & 63;
#pragma unroll
  for (int j = 0; j < 4; j++) {
    int tok = rb * 16 + j * 4 + w;
    if (tok > N_TOK) continue;
    if (tok == N_TOK) {  // zero pad row of xh
      half4t zz; zz[0] = zz[1] = zz[2] = zz[3] = (_Float16)0.f;
#pragma unroll
      for (int jj = 0; jj < 3; jj++)
        *(half4t*)(xh + (long)N_TOK * DDIM + lane * 4 + jj * 256) = zz;
      continue;
    }
    const float* xr = x + (long)tok * DDIM;
    // fp16 convert + zero the out row (replaces memset; runs before gemm2)
    f4 z4 = {0.f, 0.f, 0.f, 0.f};
#pragma unroll
    for (int jj = 0; jj < 3; jj++) {
      f4 v = *(const f4*)(xr + lane * 4 + jj * 256);
      half4t hv;
      hv[0] = (_Float16)v[0]; hv[1] = (_Float16)v[1];
      hv[2] = (_Float16)v[2]; hv[3] = (_Float16)v[3];
      *(half4t*)(xh + (long)tok * DDIM + lane * 4 + jj * 256) = hv;
      *(f4*)(out + (long)tok * DDIM + lane * 4 + jj * 256) = z4;
    }
    // logits
    float acc[8] = {0.f, 0.f, 0.f, 0.f, 0.f, 0.f, 0.f, 0.f};
#pragma unroll
    for (int i = 0; i < 12; i++) {
      float xv = xr[i * 64 + lane];
#pragma unroll
      for (int e2 = 0; e2 < 8; e2++)
        acc[e2] += xv * smem[e2 * DDIM + i * 64 + lane];
    }
#pragma unroll
    for (int e2 = 0; e2 < 8; e2++) {
      float v = acc[e2];
      v += __shfl_xor(v, 32); v += __shfl_xor(v, 16); v += __shfl_xor(v, 8);
      v += __shfl_xor(v, 4);  v += __shfl_xor(v, 2);  v += __shfl_xor(v, 1);
      acc[e2] = v;
    }
    if (lane == 0) {
      float m0 = -1e30f; int i0 = 0;
#pragma unroll
      for (int e2 = 0; e2 < 8; e2++) if (acc[e2] > m0) { m0 = acc[e2]; i0 = e2; }
      float m1 = -1e30f; int i1 = 0;
#pragma unroll
      for (int e2 = 0; e2 < 8; e2++) if (e2 != i0 && acc[e2] > m1) { m1 = acc[e2]; i1 = e2; }
      float tt = __expf(m1 - m0);
      float w0 = 1.f / (1.f + tt);
      eidx[tok * 2 + 0] = i0; eidx[tok * 2 + 1] = i1;
      wts[tok * 2 + 0] = w0;  wts[tok * 2 + 1] = 1.f - w0;
    }
  }
}

// -------------------- capacity scan (16 blocks, one per (k,e)) --------------------
__global__ __launch_bounds__(64) void scan_kernel(const int* __restrict__ eidx,
                                                  int* __restrict__ toklist,
                                                  int* __restrict__ counts) {
  int z = blockIdx.x;
  int k = z >> 3, e = z & 7;
  int lane = threadIdx.x;
  int mye[64];
#pragma unroll
  for (int c = 0; c < 64; c++) mye[c] = eidx[(c * 64 + lane) * 2 + k];
  int base = 0;
#pragma unroll 4
  for (int c = 0; c < 64; c++) {
    int n = c * 64 + lane;
    bool pred = (mye[c] == e);
    unsigned long long mask = __ballot(pred);
    if (pred) {
      int pos = base + __popcll(mask & ((1ull << lane) - 1ull));
      if (pos < CAP) toklist[z * CAPP + pos] = n;
    }
    base += __popcll(mask);
  }
  if (lane == 0) counts[z] = (base < CAP) ? base : CAP;
}

// -------------------- GEMM1 + fused SwiGLU --------------------
__global__ __launch_bounds__(256, 2) void gemm1_kernel(const _Float16* __restrict__ xh,
                                                       const _Float16* __restrict__ w1t,
                                                       const int* __restrict__ toklist,
                                                       const int* __restrict__ counts,
                                                       _Float16* __restrict__ act) {
  int i = blockIdx.x;
  int xcd = i & 7, j = i >> 3;
  int m = j % 5, ii = j / 5;
  int k = ii & 1, n = ii >> 1;
  int e = xcd, z = k * 8 + e;
  int count = counts[z];
  int m0 = m * 128;
  if (m0 >= count) return;
  int n0 = n * 128;

  __shared__ _Float16 As[128 * 64];
  __shared__ _Float16 Bs[256 * 64];
  __shared__ int toks[128];

  int t = threadIdx.x;
  if (t < 128) {
    int r = m0 + t;
    toks[t] = (r < count) ? toklist[z * CAPP + r] : N_TOK;
  }
  __syncthreads();

  int lane = t & 63, w = t >> 6;
  int l8 = lane >> 3, u8 = lane & 7;

  const _Float16* ag[4]; _Float16* al[4];
#pragma unroll
  for (int s = 0; s < 4; s++) {
    int row = w * 32 + s * 8 + l8;
    ag[s] = xh + (long)toks[row] * DDIM + ((u8 ^ (row & 7)) * 8);
    al[s] = As + row * 64 + u8 * 8;
  }
  const _Float16* bg[8]; _Float16* bl[8];
#pragma unroll
  for (int s = 0; s < 8; s++) {
    int rb = w * 64 + s * 8 + l8;
    int gr = (rb < 128) ? (n0 + rb) : (2048 + n0 + (rb - 128));
    bg[s] = w1t + ((long)e * 4096 + gr) * DDIM + ((u8 ^ (rb & 7)) * 8);
    bl[s] = Bs + rb * 64 + u8 * 8;
  }

  int q = lane >> 4, m16 = lane & 15;
  int wm = w & 1, wn = w >> 1;

  f4 zero4 = {0.f, 0.f, 0.f, 0.f};
  f4 acc[4][4][2];
#pragma unroll
  for (int rt = 0; rt < 4; rt++)
#pragma unroll
    for (int ct = 0; ct < 4; ct++) { acc[rt][ct][0] = zero4; acc[rt][ct][1] = zero4; }

  for (int kk = 0; kk < DDIM; kk += 64) {
    __syncthreads();
#pragma unroll
    for (int s = 0; s < 4; s++) { gld16(ag[s], al[s]); ag[s] += 64; }
#pragma unroll
    for (int s = 0; s < 8; s++) { gld16(bg[s], bl[s]); bg[s] += 64; }
    __syncthreads();

#pragma unroll
    for (int c = 0; c < 2; c++) {
      half8 af[4], bf[4][2];
#pragma unroll
      for (int rt = 0; rt < 4; rt++) {
        int row = wm * 64 + rt * 16 + m16;
        af[rt] = *(const half8*)(As + row * 64 + (((c * 4 + q) ^ (row & 7)) * 8));
      }
#pragma unroll
      for (int ct = 0; ct < 4; ct++) {
        int cb = wn * 64 + ct * 16 + m16;
        int ph = ((c * 4 + q) ^ (cb & 7)) * 8;
        bf[ct][0] = *(const half8*)(Bs + cb * 64 + ph);
        bf[ct][1] = *(const half8*)(Bs + (128 + cb) * 64 + ph);
      }
#pragma unroll
      for (int rt = 0; rt < 4; rt++)
#pragma unroll
        for (int ct = 0; ct < 4; ct++) {
          acc[rt][ct][0] = __builtin_amdgcn_mfma_f32_16x16x32_f16(af[rt], bf[ct][0], acc[rt][ct][0], 0, 0, 0);
          acc[rt][ct][1] = __builtin_amdgcn_mfma_f32_16x16x32_f16(af[rt], bf[ct][1], acc[rt][ct][1], 0, 0, 0);
        }
    }
  }

  long ab = (long)z * CAPP * HDIM;
#pragma unroll
  for (int rt = 0; rt < 4; rt++)
#pragma unroll
    for (int ct = 0; ct < 4; ct++)
#pragma unroll
      for (int r = 0; r < 4; r++) {
        int row = m0 + wm * 64 + rt * 16 + q * 4 + r;
        int col = n0 + wn * 64 + ct * 16 + m16;
        float h1 = acc[rt][ct][0][r], h2 = acc[rt][ct][1][r];
        float s = h2 / (1.f + __expf(-h2));
        act[ab + (long)row * HDIM + col] = (_Float16)(h1 * s);
      }
}

// -------------------- GEMM2 + weighted scatter (atomicAdd into out) --------------------
__global__ __launch_bounds__(256, 3) void gemm2_kernel(const _Float16* __restrict__ act,
                                                       const _Float16* __restrict__ w2t,
                                                       const int* __restrict__ toklist,
                                                       const int* __restrict__ counts,
                                                       const float* __restrict__ wts,
                                                       float* __restrict__ out) {
  int i = blockIdx.x;
  int xcd = i & 7, j = i >> 3;
  int m = j % 5, t2 = j / 5;
  int k = t2 & 1, n = t2 >> 1;
  int e = xcd, z = k * 8 + e;
  int count = counts[z];
  int m0 = m * 128;
  if (m0 >= count) return;
  int n0 = n * 128;

  __shared__ _Float16 As[128 * 64];
  __shared__ _Float16 Bs[128 * 64];
  __shared__ int toksL[128];
  __shared__ float wrow[128];

  int t = threadIdx.x;
  if (t < 128) {
    int r = m0 + t;
    if (r < count) {
      int tok = toklist[z * CAPP + r];
      toksL[t] = tok;
      wrow[t] = wts[tok * 2 + k];
    } else {
      toksL[t] = -1;
      wrow[t] = 0.f;
    }
  }
  __syncthreads();

  int lane = t & 63, w = t >> 6;
  int l8 = lane >> 3, u8 = lane & 7;

  const _Float16* ag[4]; _Float16* al[4];
#pragma unroll
  for (int s = 0; s < 4; s++) {
    int row = w * 32 + s * 8 + l8;
    ag[s] = act + ((long)z * CAPP + m0 + row) * HDIM + ((u8 ^ (row & 7)) * 8);
    al[s] = As + row * 64 + u8 * 8;
  }
  const _Float16* bg[4]; _Float16* bl[4];
#pragma unroll
  for (int s = 0; s < 4; s++) {
    int rb = w * 32 + s * 8 + l8;
    bg[s] = w2t + ((long)e * DDIM + n0 + rb) * HDIM + ((u8 ^ (rb & 7)) * 8);
    bl[s] = Bs + rb * 64 + u8 * 8;
  }

  int q = lane >> 4, m16 = lane & 15;
  int wm = w & 1, wn = w >> 1;

  f4 zero4 = {0.f, 0.f, 0.f, 0.f};
  f4 acc[4][4];
#pragma unroll
  for (int rt = 0; rt < 4; rt++)
#pragma unroll
    for (int ct = 0; ct < 4; ct++) acc[rt][ct] = zero4;

  for (int kk = 0; kk < HDIM; kk += 64) {
    __syncthreads();
#pragma unroll
    for (int s = 0; s < 4; s++) { gld16(ag[s], al[s]); ag[s] += 64; }
#pragma unroll
    for (int s = 0; s < 4; s++) { gld16(bg[s], bl[s]); bg[s] += 64; }
    __syncthreads();

#pragma unroll
    for (int c = 0; c < 2; c++) {
      half8 af[4], bf[4];
#pragma unroll
      for (int rt = 0; rt < 4; rt++) {
        int row = wm * 64 + rt * 16 + m16;
        af[rt] = *(const half8*)(As + row * 64 + (((c * 4 + q) ^ (row & 7)) * 8));
      }
#pragma unroll
      for (int ct = 0; ct < 4; ct++) {
        int cb = wn * 64 + ct * 16 + m16;
        bf[ct] = *(const half8*)(Bs + cb * 64 + (((c * 4 + q) ^ (cb & 7)) * 8));
      }
#pragma unroll
      for (int rt = 0; rt < 4; rt++)
#pragma unroll
        for (int ct = 0; ct < 4; ct++)
          acc[rt][ct] = __builtin_amdgcn_mfma_f32_16x16x32_f16(af[rt], bf[ct], acc[rt][ct], 0, 0, 0);
    }
  }

#pragma unroll
  for (int rt = 0; rt < 4; rt++)
#pragma unroll
    for (int ct = 0; ct < 4; ct++)
#pragma unroll
      for (int r = 0; r < 4; r++) {
        int lr = wm * 64 + rt * 16 + q * 4 + r;
        int tok = toksL[lr];
        if (tok >= 0) {
          int col = n0 + wn * 64 + ct * 16 + m16;
          atomicAdd(&out[(long)tok * DDIM + col], wrow[lr] * acc[rt][ct][r]);
        }
      }
}

// -------------------- launch --------------------

extern "C" void kernel_launch(void* const* d_in, const int* in_sizes, int n_in,
                              void* d_out, int out_size, void* d_ws, size_t ws_size,
                              hipStream_t stream) {
  const float* x  = (const float*)d_in[0];
  const float* Wg = (const float*)d_in[1];
  const float* W1 = (const float*)d_in[2];
  const float* W2 = (const float*)d_in[3];
  float* out = (float*)d_out;
  char* ws = (char*)d_ws;

  _Float16* xh   = (_Float16*)(ws + XH_OFF);
  _Float16* w1t  = (_Float16*)(ws + W1T_OFF);
  _Float16* w2t  = (_Float16*)(ws + W2T_OFF);
  _Float16* actb = (_Float16*)(ws + ACT_OFF);
  int* eidx      = (int*)(ws + EIDX_OFF);
  float* wts     = (float*)(ws + WTS_OFF);
  int* toklist   = (int*)(ws + TOKL_OFF);
  int* counts    = (int*)(ws + CNT_OFF);

  prep_kernel<<<CVT1_BLOCKS + CVT2_BLOCKS + ROUT_BLOCKS, 256, 0, stream>>>(
      x, Wg, W1, W2, xh, w1t, w2t, eidx, wts, out);
  scan_kernel<<<16, 64, 0, stream>>>(eidx, toklist, counts);
  gemm1_kernel<<<1280, 256, 0, stream>>>(xh, w1t, toklist, counts, actb);
  gemm2_kernel<<<480, 256, 0, stream>>>(actb, w2t, toklist, counts, wts, out);
}